// Round 1
// 1470.086 us; speedup vs baseline: 1.0012x; 1.0012x over previous
//
#include <hip/hip_runtime.h>
#include <hip/hip_bf16.h>

// MoEReadout round 5: pair-bucketed (15 combos) 32-atom tiles.
//  - k_router/k_scatter: block-aggregated atomics (LDS histogram).
//  - k_moe: nontemporal X loads + Y stores (keep weights L2-resident),
//    ping-pong register prefetch of W fragments.
//  - NEW: bijective XCD-chunked blockIdx swizzle (m204 form). Tiles are
//    bucket-sorted by expert pair; giving each XCD a contiguous tile range
//    makes its concurrent working set ~1 pair (2 routed + 2 shared experts
//    = 3 MB bf16) < 4 MB per-XCD L2, instead of all 8 experts (6.3 MB)
//    thrashing to L3 at ~600 cy latency.

typedef __attribute__((ext_vector_type(8))) short short8;   // 8 x bf16
typedef __attribute__((ext_vector_type(4))) float f32x4;    // MFMA acc / 16B load

#define IN_F 512
#define HID  512
#define OUT_F 256
#define TILE 32

__device__ inline unsigned short f2bf(float f) {
    __hip_bfloat16 h = __float2bfloat16(f);
    return *reinterpret_cast<unsigned short*>(&h);
}

// ---------- weight conversion ----------
__global__ void k_cvt_w1(const float* __restrict__ rW1, const float* __restrict__ sW1,
                         unsigned short* __restrict__ dst) {
    int i = blockIdx.x * 256 + threadIdx.x;          // < 8*512*512
    int e = i >> 18;
    int off = i & ((1 << 18) - 1);
    float v = (e < 6) ? rW1[(size_t)e * 262144 + off]
                      : sW1[(size_t)(e - 6) * 262144 + off];
    dst[i] = f2bf(v);
}

__global__ void k_cvt_w2(const float* __restrict__ rW2, const float* __restrict__ sW2,
                         unsigned short* __restrict__ dst) {
    int i = blockIdx.x * 256 + threadIdx.x;          // < 8*256*512
    int e = i >> 17;
    int off = i & ((1 << 17) - 1);
    float v = (e < 6) ? rW2[(size_t)e * 131072 + off]
                      : sW2[(size_t)(e - 6) * 131072 + off];
    dst[i] = f2bf(v);
}

// ---------- bucket state init ----------
__global__ void k_fill(int* __restrict__ counts, int* __restrict__ cursors,
                       int* __restrict__ idxl, int* __restrict__ tile_pair,
                       int CAP, int TMAX) {
    int i = blockIdx.x * 256 + threadIdx.x;
    if (i < 16) { counts[i] = 0; cursors[i] = 0; }
    if (i < TMAX) tile_pair[i] = -1;
    if (i < CAP) idxl[i] = -1;
}

// ---------- router: top-2 -> pair id + gates (block-aggregated histogram) ----------
__global__ void k_router(const int* __restrict__ species, const float* __restrict__ emb,
                         const float* __restrict__ Wr,
                         int* __restrict__ pid, float* __restrict__ gA, float* __restrict__ gB,
                         int* __restrict__ counts, int N) {
    __shared__ int lcnt[16];
    int tid = threadIdx.x;
    if (tid < 16) lcnt[tid] = 0;
    __syncthreads();
    int i = blockIdx.x * 256 + tid;
    if (i < N) {
        int z = species[i];
        float u[16];
#pragma unroll
        for (int k = 0; k < 16; ++k) {
            float v = emb[z * 16 + k];
            u[k] = v / (1.f + __expf(-v));               // silu
        }
        float s[6];
        float mx = -1e30f;
#pragma unroll
        for (int e = 0; e < 6; ++e) {
            float a = 0.f;
#pragma unroll
            for (int k = 0; k < 16; ++k) a += u[k] * Wr[e * 16 + k];
            s[e] = a;
            mx = fmaxf(mx, a);
        }
        float sum = 0.f;
#pragma unroll
        for (int e = 0; e < 6; ++e) { s[e] = __expf(s[e] - mx); sum += s[e]; }
        float inv = 1.f / sum;
        int i0 = 0;
#pragma unroll
        for (int e = 1; e < 6; ++e) if (s[e] > s[i0]) i0 = e;
        int i1 = (i0 == 0) ? 1 : 0;
#pragma unroll
        for (int e = 0; e < 6; ++e) if (e != i0 && s[e] > s[i1]) i1 = e;
        float g0 = s[i0] * inv, g1 = s[i1] * inv;
        int a = min(i0, i1), b = max(i0, i1);
        const int PB[5] = {0, 5, 9, 12, 14};
        int p = PB[a] + (b - a - 1);
        pid[i] = p;
        gA[i] = (a == i0) ? g0 : g1;
        gB[i] = (a == i0) ? g1 : g0;
        atomicAdd(&lcnt[p], 1);          // LDS atomic — cheap
    }
    __syncthreads();
    if (tid < 15 && lcnt[tid] > 0) atomicAdd(&counts[tid], lcnt[tid]);
}

// ---------- scan: padded bucket offsets + tile->pair map ----------
__global__ void k_scan(const int* __restrict__ counts, int* __restrict__ offs,
                       int* __restrict__ tile_pair, int TMAX) {
    __shared__ int so[16];
    if (threadIdx.x == 0) {
        int acc = 0;
        for (int p = 0; p < 15; ++p) { so[p] = acc; acc += (counts[p] + 31) & ~31; }
        so[15] = acc;
        for (int p = 0; p < 16; ++p) offs[p] = so[p];
    }
    __syncthreads();
    for (int t = threadIdx.x; t < TMAX; t += blockDim.x) {
        int t32 = t * 32;
        if (t32 < so[15]) {
            int p = 0;
            while (!(t32 >= so[p] && t32 < so[p + 1])) ++p;
            tile_pair[t] = p;
        }
    }
}

// ---------- scatter atoms into pair buckets (block-aggregated) ----------
__global__ void k_scatter(const int* __restrict__ pid, const float* __restrict__ gA,
                          const float* __restrict__ gB, const int* __restrict__ offs,
                          int* __restrict__ cursors, int* __restrict__ idxl,
                          float* __restrict__ gAl, float* __restrict__ gBl, int N) {
    __shared__ int lcnt[16], lbase[16];
    int tid = threadIdx.x;
    if (tid < 16) lcnt[tid] = 0;
    __syncthreads();
    int i = blockIdx.x * 256 + tid;
    int p = -1, rank = 0;
    if (i < N) { p = pid[i]; rank = atomicAdd(&lcnt[p], 1); }
    __syncthreads();
    if (tid < 15 && lcnt[tid] > 0) lbase[tid] = atomicAdd(&cursors[tid], lcnt[tid]);
    __syncthreads();
    if (i < N) {
        int slot = offs[p] + lbase[p] + rank;
        idxl[slot] = i; gAl[slot] = gA[i]; gBl[slot] = gB[i];
    }
}

// ---------- fused MoE MLP over pair-homogeneous 32-atom tiles ----------
// LDS ~50.6 KB -> 3 blocks/CU (12 waves). 4 waves; per H-chunk of 256 cols a
// wave owns 64 H cols; OUT cols [64wv, 64wv+64) persistent in registers.
__global__ __launch_bounds__(256, 3) void k_moe(
    const float* __restrict__ X,
    const unsigned short* __restrict__ W1all,    // [8][512][512] bf16
    const unsigned short* __restrict__ W2all,    // [8][256][512] bf16
    const int* __restrict__ idxl, const float* __restrict__ gAl,
    const float* __restrict__ gBl, const int* __restrict__ tile_pair,
    const float* __restrict__ rb1, const float* __restrict__ rb2,
    const float* __restrict__ sb1, const float* __restrict__ sb2,
    float* __restrict__ Y)
{
    // Bijective XCD-chunked swizzle (m204): blocks with the same dispatch
    // XCD (blockIdx%8) get a CONTIGUOUS tile range. Tiles are sorted by
    // expert pair, so each XCD's live weight working set is ~1 pair
    // (2 routed + 2 shared = 3 MB) < 4 MB per-XCD L2.
    int t;
    {
        const int nwg = (int)gridDim.x;
        const int q = nwg >> 3, r = nwg & 7;
        const int xcd = (int)blockIdx.x & 7;
        const int idx = (int)blockIdx.x >> 3;
        t = (xcd < r ? xcd * (q + 1) : r * (q + 1) + (xcd - r) * q) + idx;
    }
    const int p = tile_pair[t];
    if (p < 0) return;
    int ea = 0, eb = 1;
    {
        int pp = p;
#pragma unroll
        for (int a = 0; a < 5; ++a) {
            int span = 5 - a;
            if (pp < span) { ea = a; eb = a + 1 + pp; break; }
            pp -= span;
        }
    }

    __shared__ unsigned short xs[TILE][520];
    __shared__ unsigned short hs[TILE][264];
    __shared__ float gsA[TILE], gsB[TILE];
    __shared__ int idxs[TILE];

    const int tid = threadIdx.x;
    if (tid < TILE) {
        int slot = t * TILE + tid;
        int gi = idxl[slot];
        idxs[tid] = gi;
        gsA[tid] = (gi >= 0) ? gAl[slot] : 0.f;
        gsB[tid] = (gi >= 0) ? gBl[slot] : 0.f;
    }
    __syncthreads();

    // stage X tile (fp32 -> bf16), nontemporal (don't evict weights from L2)
    for (int i = tid; i < TILE * 128; i += 256) {
        int r = i >> 7, c4 = i & 127;
        int gi = idxs[r]; if (gi < 0) gi = 0;
        f32x4 v = __builtin_nontemporal_load(
            reinterpret_cast<const f32x4*>(X + (size_t)gi * IN_F) + c4);
        ushort4 pk;
        pk.x = f2bf(v.x); pk.y = f2bf(v.y); pk.z = f2bf(v.z); pk.w = f2bf(v.w);
        *reinterpret_cast<ushort4*>(&xs[r][c4 * 4]) = pk;
    }
    __syncthreads();

    const int wv = tid >> 6;
    const int lane = tid & 63;
    const int quad = lane >> 4;
    const int l16 = lane & 15;

    f32x4 outacc[2][4] = {};   // 32 x 64 per wave, cols [64wv, 64wv+64)

    for (int ei = 0; ei < 4; ++ei) {
        const int ex = (ei == 0) ? ea : (ei == 1) ? eb : (ei + 4);  // 6,7 shared
        const unsigned short* W1 = W1all + (size_t)ex * (HID * IN_F);
        const unsigned short* W2 = W2all + (size_t)ex * (OUT_F * HID);
        const float* b1 = (ex < 6) ? rb1 + ex * HID   : sb1 + (ex - 6) * HID;
        const float* b2 = (ex < 6) ? rb2 + ex * OUT_F : sb2 + (ex - 6) * OUT_F;

        float gr[8];
#pragma unroll
        for (int mt = 0; mt < 2; ++mt)
#pragma unroll
            for (int r = 0; r < 4; ++r) {
                int row = mt * 16 + quad * 4 + r;
                gr[mt * 4 + r] = (ei == 0) ? gsA[row] : (ei == 1) ? gsB[row] : 1.f;
            }

        // per-lane W2 row pointers (fixed for the whole expert)
        const unsigned short* w2row[4];
#pragma unroll
        for (int nt = 0; nt < 4; ++nt)
            w2row[nt] = W2 + (size_t)(wv * 64 + nt * 16 + l16) * HID + quad * 8;

        for (int j = 0; j < 2; ++j) {              // H column chunks of 256
            const int hbase = j * 256 + wv * 64;   // this wave's H cols
            // per-lane W1 row pointers for this chunk
            const unsigned short* w1row[4];
#pragma unroll
            for (int nt = 0; nt < 4; ++nt)
                w1row[nt] = W1 + (size_t)(hbase + nt * 16 + l16) * IN_F + quad * 8;

            // ---- phase A: H' chunk = gate * silu(X @ W1^T + b1)
            // ping-pong register prefetch: batch of 4 W loads in flight
            f32x4 acc[2][4] = {};
            short8 bp[4], bq[4], a0[2], a1[2];
#pragma unroll
            for (int nt = 0; nt < 4; ++nt)
                bp[nt] = *reinterpret_cast<const short8*>(w1row[nt]);
#pragma unroll
            for (int kk = 0; kk < IN_F; kk += 64) {
#pragma unroll
                for (int nt = 0; nt < 4; ++nt)
                    bq[nt] = *reinterpret_cast<const short8*>(w1row[nt] + kk + 32);
#pragma unroll
                for (int mt = 0; mt < 2; ++mt)
                    a0[mt] = *reinterpret_cast<const short8*>(&xs[mt * 16 + l16][kk + quad * 8]);
#pragma unroll
                for (int mt = 0; mt < 2; ++mt)
#pragma unroll
                    for (int nt = 0; nt < 4; ++nt)
                        acc[mt][nt] = __builtin_amdgcn_mfma_f32_16x16x32_bf16(
                            a0[mt], bp[nt], acc[mt][nt], 0, 0, 0);
                if (kk + 64 < IN_F) {
#pragma unroll
                    for (int nt = 0; nt < 4; ++nt)
                        bp[nt] = *reinterpret_cast<const short8*>(w1row[nt] + kk + 64);
                }
#pragma unroll
                for (int mt = 0; mt < 2; ++mt)
                    a1[mt] = *reinterpret_cast<const short8*>(&xs[mt * 16 + l16][kk + 32 + quad * 8]);
#pragma unroll
                for (int mt = 0; mt < 2; ++mt)
#pragma unroll
                    for (int nt = 0; nt < 4; ++nt)
                        acc[mt][nt] = __builtin_amdgcn_mfma_f32_16x16x32_bf16(
                            a1[mt], bq[nt], acc[mt][nt], 0, 0, 0);
            }
#pragma unroll
            for (int mt = 0; mt < 2; ++mt)
#pragma unroll
                for (int nt = 0; nt < 4; ++nt) {
                    int hcol = wv * 64 + nt * 16 + l16;        // hs col
                    float bb = b1[hbase + nt * 16 + l16];
#pragma unroll
                    for (int r = 0; r < 4; ++r) {
                        int row = mt * 16 + quad * 4 + r;
                        float v = acc[mt][nt][r] + bb;
                        float h = v / (1.f + __expf(-v));
                        hs[row][hcol] = f2bf(h * gr[mt * 4 + r]);
                    }
                }
            __syncthreads();

            // ---- phase B: OUT += H'chunk @ W2^T (K=256), same prefetch scheme
#pragma unroll
            for (int nt = 0; nt < 4; ++nt)
                bp[nt] = *reinterpret_cast<const short8*>(w2row[nt] + j * 256);
#pragma unroll
            for (int kk = 0; kk < 256; kk += 64) {
#pragma unroll
                for (int nt = 0; nt < 4; ++nt)
                    bq[nt] = *reinterpret_cast<const short8*>(w2row[nt] + j * 256 + kk + 32);
#pragma unroll
                for (int mt = 0; mt < 2; ++mt)
                    a0[mt] = *reinterpret_cast<const short8*>(&hs[mt * 16 + l16][kk + quad * 8]);
#pragma unroll
                for (int mt = 0; mt < 2; ++mt)
#pragma unroll
                    for (int nt = 0; nt < 4; ++nt)
                        outacc[mt][nt] = __builtin_amdgcn_mfma_f32_16x16x32_bf16(
                            a0[mt], bp[nt], outacc[mt][nt], 0, 0, 0);
                if (kk + 64 < 256) {
#pragma unroll
                    for (int nt = 0; nt < 4; ++nt)
                        bp[nt] = *reinterpret_cast<const short8*>(w2row[nt] + j * 256 + kk + 64);
                }
#pragma unroll
                for (int mt = 0; mt < 2; ++mt)
                    a1[mt] = *reinterpret_cast<const short8*>(&hs[mt * 16 + l16][kk + 32 + quad * 8]);
#pragma unroll
                for (int mt = 0; mt < 2; ++mt)
#pragma unroll
                    for (int nt = 0; nt < 4; ++nt)
                        outacc[mt][nt] = __builtin_amdgcn_mfma_f32_16x16x32_bf16(
                            a1[mt], bq[nt], outacc[mt][nt], 0, 0, 0);
            }
            __syncthreads();
        }

        // ---- + gate * b2
#pragma unroll
        for (int mt = 0; mt < 2; ++mt)
#pragma unroll
            for (int nt = 0; nt < 4; ++nt) {
                float bb = b2[wv * 64 + nt * 16 + l16];
#pragma unroll
                for (int r = 0; r < 4; ++r)
                    outacc[mt][nt][r] += gr[mt * 4 + r] * bb;
            }
    }

    // write Y nontemporal (write-once stream; keep L2 for weights)
#pragma unroll
    for (int mt = 0; mt < 2; ++mt)
#pragma unroll
        for (int nt = 0; nt < 4; ++nt)
#pragma unroll
            for (int r = 0; r < 4; ++r) {
                int row = mt * 16 + quad * 4 + r;
                int gi = idxs[row];
                if (gi >= 0)
                    __builtin_nontemporal_store(outacc[mt][nt][r],
                        Y + (size_t)gi * OUT_F + wv * 64 + nt * 16 + l16);
            }
}

extern "C" void kernel_launch(void* const* d_in, const int* in_sizes, int n_in,
                              void* d_out, int out_size, void* d_ws, size_t ws_size,
                              hipStream_t stream) {
    const float* X       = (const float*)d_in[0];
    const int*   species = (const int*)d_in[1];
    const float* emb     = (const float*)d_in[2];
    const float* Wr      = (const float*)d_in[3];
    const float* rW1     = (const float*)d_in[4];
    const float* rb1     = (const float*)d_in[5];
    const float* rW2     = (const float*)d_in[6];
    const float* rb2     = (const float*)d_in[7];
    const float* sW1     = (const float*)d_in[8];
    const float* sb1     = (const float*)d_in[9];
    const float* sW2     = (const float*)d_in[10];
    const float* sb2     = (const float*)d_in[11];
    float* Y = (float*)d_out;
    const int N = in_sizes[1];

    const int CAP  = N + 15 * 32;
    const int TMAX = CAP / 32;

    size_t o = 0;
    auto take = [&](size_t bytes) { size_t r = o; o += (bytes + 255) & ~(size_t)255; return r; };
    char* ws = (char*)d_ws;
    unsigned short* w1bf   = (unsigned short*)(ws + take((size_t)8 * HID * IN_F * 2));
    unsigned short* w2bf   = (unsigned short*)(ws + take((size_t)8 * OUT_F * HID * 2));
    int*   pid      = (int*)  (ws + take((size_t)N * 4));
    float* gA       = (float*)(ws + take((size_t)N * 4));
    float* gB       = (float*)(ws + take((size_t)N * 4));
    int*   counts   = (int*)  (ws + take(64));
    int*   cursors  = (int*)  (ws + take(64));
    int*   offs     = (int*)  (ws + take(64));
    int*   idxl     = (int*)  (ws + take((size_t)CAP * 4));
    float* gAl      = (float*)(ws + take((size_t)CAP * 4));
    float* gBl      = (float*)(ws + take((size_t)CAP * 4));
    int*   tile_pair= (int*)  (ws + take((size_t)TMAX * 4));

    k_cvt_w1<<<(8 * HID * IN_F) / 256, 256, 0, stream>>>(rW1, sW1, w1bf);
    k_cvt_w2<<<(8 * OUT_F * HID) / 256, 256, 0, stream>>>(rW2, sW2, w2bf);
    k_fill<<<(CAP + 255) / 256, 256, 0, stream>>>(counts, cursors, idxl, tile_pair, CAP, TMAX);
    k_router<<<(N + 255) / 256, 256, 0, stream>>>(species, emb, Wr, pid, gA, gB, counts, N);
    k_scan<<<1, 256, 0, stream>>>(counts, offs, tile_pair, TMAX);
    k_scatter<<<(N + 255) / 256, 256, 0, stream>>>(pid, gA, gB, offs, cursors, idxl, gAl, gBl, N);
    k_moe<<<TMAX, 256, 0, stream>>>(X, w1bf, w2bf, idxl, gAl, gBl, tile_pair,
                                    rb1, rb2, sb1, sb2, Y);
}

// Round 2
// 1002.389 us; speedup vs baseline: 1.4683x; 1.4666x over previous
//
#include <hip/hip_runtime.h>
#include <hip/hip_bf16.h>

// MoEReadout round 6: pair-bucketed 64-atom tiles, 8-wave blocks,
// weights streamed through double-buffered LDS via global_load_lds.
//  - k_cvt_w1/w2 pre-pack weights into fragment-linear 16KB chunks
//    [ex][j][kq][row256][col32] so each DMA instr is a contiguous 1KB copy
//    with wave-uniform addressing (no per-lane 64-bit pointer arithmetic).
//  - k_moe: 2-phase pipeline per K-step (stage next chunk -> ds_read+MFMA
//    current -> barrier). In-flight weight data parks in LDS, not VGPRs.
//  - TILE=64 halves weight traffic per atom vs TILE=32.
//  - XCD-chunked bijective blockIdx swizzle kept (weights L2-resident).

typedef __attribute__((ext_vector_type(8))) short short8;   // 8 x bf16
typedef __attribute__((ext_vector_type(4))) float f32x4;    // MFMA acc / 16B load

#define IN_F 512
#define HID  512
#define OUT_F 256
#define TILE 64

__device__ inline unsigned short f2bf(float f) {
    __hip_bfloat16 h = __float2bfloat16(f);
    return *reinterpret_cast<unsigned short*>(&h);
}

// CK-style address-space casts for global_load_lds (direct-to-LDS DMA).
__device__ __forceinline__ void dma16(const unsigned short* g, unsigned short* l) {
    __builtin_amdgcn_global_load_lds(
        (const __attribute__((address_space(1))) unsigned int*)(unsigned long long)(const void*)g,
        (__attribute__((address_space(3))) unsigned int*)(unsigned int)(unsigned long long)(void*)l,
        16, 0, 0);
}

// Stage one 16KB chunk (256 rows x 32 bf16 cols, row-linear) into LDS.
// Wave w copies 2KB; global and LDS images are identical (packed layout).
__device__ __forceinline__ void stage_chunk(const unsigned short* gbase,
                                            unsigned short* lbase,
                                            int w, int lane) {
    dma16(gbase + w * 1024 +       lane * 8, lbase + w * 1024);
    dma16(gbase + w * 1024 + 512 + lane * 8, lbase + w * 1024 + 512);
}

// ---------- weight conversion + fragment packing ----------
// W1 packed: [ex(8)][j(2)][kq(16)][row(256)][col(32)]  (row=H idx in j-chunk,
// col=IN_F idx in kq-chunk). 2,097,152 shorts total.
__global__ void k_cvt_w1(const float* __restrict__ rW1, const float* __restrict__ sW1,
                         unsigned short* __restrict__ dst) {
    int i = blockIdx.x * 256 + threadIdx.x;
    int col = i & 31;
    int row = (i >> 5) & 255;
    int kq  = (i >> 13) & 15;
    int j   = (i >> 17) & 1;
    int ex  = i >> 18;
    int hrow = j * 256 + row;
    int kcol = kq * 32 + col;
    float v = (ex < 6) ? rW1[((size_t)ex * 512 + hrow) * 512 + kcol]
                       : sW1[((size_t)(ex - 6) * 512 + hrow) * 512 + kcol];
    dst[i] = f2bf(v);
}

// W2 packed: [ex(8)][j(2)][kq(8)][row(256)][col(32)] (row=OUT idx,
// col=HID idx within j*256+kq*32 chunk). 1,048,576 shorts total.
__global__ void k_cvt_w2(const float* __restrict__ rW2, const float* __restrict__ sW2,
                         unsigned short* __restrict__ dst) {
    int i = blockIdx.x * 256 + threadIdx.x;
    int col = i & 31;
    int row = (i >> 5) & 255;
    int kq  = (i >> 13) & 7;
    int j   = (i >> 16) & 1;
    int ex  = i >> 17;
    int kcol = j * 256 + kq * 32 + col;
    float v = (ex < 6) ? rW2[((size_t)ex * 256 + row) * 512 + kcol]
                       : sW2[((size_t)(ex - 6) * 256 + row) * 512 + kcol];
    dst[i] = f2bf(v);
}

// ---------- bucket state init ----------
__global__ void k_fill(int* __restrict__ counts, int* __restrict__ cursors,
                       int* __restrict__ idxl, int* __restrict__ tile_pair,
                       int CAP, int TMAX) {
    int i = blockIdx.x * 256 + threadIdx.x;
    if (i < 16) { counts[i] = 0; cursors[i] = 0; }
    if (i < TMAX) tile_pair[i] = -1;
    if (i < CAP) idxl[i] = -1;
}

// ---------- router: top-2 -> pair id + gates ----------
__global__ void k_router(const int* __restrict__ species, const float* __restrict__ emb,
                         const float* __restrict__ Wr,
                         int* __restrict__ pid, float* __restrict__ gA, float* __restrict__ gB,
                         int* __restrict__ counts, int N) {
    __shared__ int lcnt[16];
    int tid = threadIdx.x;
    if (tid < 16) lcnt[tid] = 0;
    __syncthreads();
    int i = blockIdx.x * 256 + tid;
    if (i < N) {
        int z = species[i];
        float u[16];
#pragma unroll
        for (int k = 0; k < 16; ++k) {
            float v = emb[z * 16 + k];
            u[k] = v / (1.f + __expf(-v));               // silu
        }
        float s[6];
        float mx = -1e30f;
#pragma unroll
        for (int e = 0; e < 6; ++e) {
            float a = 0.f;
#pragma unroll
            for (int k = 0; k < 16; ++k) a += u[k] * Wr[e * 16 + k];
            s[e] = a;
            mx = fmaxf(mx, a);
        }
        float sum = 0.f;
#pragma unroll
        for (int e = 0; e < 6; ++e) { s[e] = __expf(s[e] - mx); sum += s[e]; }
        float inv = 1.f / sum;
        int i0 = 0;
#pragma unroll
        for (int e = 1; e < 6; ++e) if (s[e] > s[i0]) i0 = e;
        int i1 = (i0 == 0) ? 1 : 0;
#pragma unroll
        for (int e = 0; e < 6; ++e) if (e != i0 && s[e] > s[i1]) i1 = e;
        float g0 = s[i0] * inv, g1 = s[i1] * inv;
        int a = min(i0, i1), b = max(i0, i1);
        const int PB[5] = {0, 5, 9, 12, 14};
        int p = PB[a] + (b - a - 1);
        pid[i] = p;
        gA[i] = (a == i0) ? g0 : g1;
        gB[i] = (a == i0) ? g1 : g0;
        atomicAdd(&lcnt[p], 1);
    }
    __syncthreads();
    if (tid < 15 && lcnt[tid] > 0) atomicAdd(&counts[tid], lcnt[tid]);
}

// ---------- scan: 64-padded bucket offsets + tile->pair map ----------
__global__ void k_scan(const int* __restrict__ counts, int* __restrict__ offs,
                       int* __restrict__ tile_pair, int TMAX) {
    __shared__ int so[16];
    if (threadIdx.x == 0) {
        int acc = 0;
        for (int p = 0; p < 15; ++p) { so[p] = acc; acc += (counts[p] + 63) & ~63; }
        so[15] = acc;
        for (int p = 0; p < 16; ++p) offs[p] = so[p];
    }
    __syncthreads();
    for (int t = threadIdx.x; t < TMAX; t += blockDim.x) {
        int t64 = t * 64;
        if (t64 < so[15]) {
            int p = 0;
            while (!(t64 >= so[p] && t64 < so[p + 1])) ++p;
            tile_pair[t] = p;
        }
    }
}

// ---------- scatter atoms into pair buckets ----------
__global__ void k_scatter(const int* __restrict__ pid, const float* __restrict__ gA,
                          const float* __restrict__ gB, const int* __restrict__ offs,
                          int* __restrict__ cursors, int* __restrict__ idxl,
                          float* __restrict__ gAl, float* __restrict__ gBl, int N) {
    __shared__ int lcnt[16], lbase[16];
    int tid = threadIdx.x;
    if (tid < 16) lcnt[tid] = 0;
    __syncthreads();
    int i = blockIdx.x * 256 + tid;
    int p = -1, rank = 0;
    if (i < N) { p = pid[i]; rank = atomicAdd(&lcnt[p], 1); }
    __syncthreads();
    if (tid < 15 && lcnt[tid] > 0) lbase[tid] = atomicAdd(&cursors[tid], lcnt[tid]);
    __syncthreads();
    if (i < N) {
        int slot = offs[p] + lbase[p] + rank;
        idxl[slot] = i; gAl[slot] = gA[i]; gBl[slot] = gB[i];
    }
}

// ---------- fused MoE MLP over pair-homogeneous 64-atom tiles ----------
// 512 threads = 8 waves (mw = w>>2 selects atom half, nw = w&3 selects the
// 64-col group). LDS ~134KB -> 1 block/CU (2 waves/SIMD). Weights stream
// through a 2x16KB double buffer via global_load_lds.
__global__ __launch_bounds__(512, 2) void k_moe(
    const float* __restrict__ X,
    const unsigned short* __restrict__ W1pk,     // packed, see k_cvt_w1
    const unsigned short* __restrict__ W2pk,     // packed, see k_cvt_w2
    const int* __restrict__ idxl, const float* __restrict__ gAl,
    const float* __restrict__ gBl, const int* __restrict__ tile_pair,
    const float* __restrict__ rb1, const float* __restrict__ rb2,
    const float* __restrict__ sb1, const float* __restrict__ sb2,
    float* __restrict__ Y)
{
    // Bijective XCD-chunked swizzle (m204): each XCD gets a contiguous
    // tile range; tiles are bucket-sorted by pair -> per-XCD working set
    // ~1 pair (3MB) < 4MB L2.
    int t;
    {
        const int nwg = (int)gridDim.x;
        const int q = nwg >> 3, r = nwg & 7;
        const int xcd = (int)blockIdx.x & 7;
        const int idx = (int)blockIdx.x >> 3;
        t = (xcd < r ? xcd * (q + 1) : r * (q + 1) + (xcd - r) * q) + idx;
    }
    const int p = tile_pair[t];
    if (p < 0) return;
    int ea = 0, eb = 1;
    {
        int pp = p;
#pragma unroll
        for (int a = 0; a < 5; ++a) {
            int span = 5 - a;
            if (pp < span) { ea = a; eb = a + 1 + pp; break; }
            pp -= span;
        }
    }

    __shared__ __align__(16) unsigned short xs[TILE][520];     // 66.6 KB
    __shared__ __align__(16) unsigned short hs[TILE][264];     // 33.8 KB
    __shared__ __align__(16) unsigned short wlds[2][8192];     // 32 KB dbuf
    __shared__ float gsA[TILE], gsB[TILE];
    __shared__ int idxs[TILE];

    const int tid = threadIdx.x;
    if (tid < TILE) {
        int slot = t * TILE + tid;
        int gi = idxl[slot];
        idxs[tid] = gi;
        gsA[tid] = (gi >= 0) ? gAl[slot] : 0.f;
        gsB[tid] = (gi >= 0) ? gBl[slot] : 0.f;
    }
    __syncthreads();

    // stage X tile (fp32 -> bf16), nontemporal
    for (int i = tid; i < TILE * 128; i += 512) {
        int r = i >> 7, c4 = i & 127;
        int gi = idxs[r]; if (gi < 0) gi = 0;
        f32x4 v = __builtin_nontemporal_load(
            reinterpret_cast<const f32x4*>(X + (size_t)gi * IN_F) + c4);
        ushort4 pk;
        pk.x = f2bf(v.x); pk.y = f2bf(v.y); pk.z = f2bf(v.z); pk.w = f2bf(v.w);
        *reinterpret_cast<ushort4*>(&xs[r][c4 * 4]) = pk;
    }

    const int w    = tid >> 6;        // wave 0..7
    const int lane = tid & 63;
    const int mw   = w >> 2;          // atom half (0..1)
    const int nw   = w & 3;           // 64-col group (0..3)
    const int quad = lane >> 4;
    const int l16  = lane & 15;

    f32x4 outacc[2][4] = {};          // 32 atoms x 64 out cols per wave

    for (int ei = 0; ei < 4; ++ei) {
        const int ex = (ei == 0) ? ea : (ei == 1) ? eb : (ei + 4);  // 6,7 shared
        const float* b1 = (ex < 6) ? rb1 + ex * HID   : sb1 + (ex - 6) * HID;
        const float* b2 = (ex < 6) ? rb2 + ex * OUT_F : sb2 + (ex - 6) * OUT_F;

        float gr[8];
#pragma unroll
        for (int mt = 0; mt < 2; ++mt)
#pragma unroll
            for (int r = 0; r < 4; ++r) {
                int row = mw * 32 + mt * 16 + quad * 4 + r;
                gr[mt * 4 + r] = (ei == 0) ? gsA[row] : (ei == 1) ? gsB[row] : 1.f;
            }

        for (int j = 0; j < 2; ++j) {              // H column chunks of 256
            // ---- phase A: H' chunk = gate * silu(X @ W1^T + b1)
            const unsigned short* w1c = W1pk + ((size_t)ex * 2 + j) * (16 * 8192);
            stage_chunk(w1c, wlds[0], w, lane);
            __syncthreads();                       // drains DMA + xs/hs writes

            f32x4 acc[2][4] = {};
#pragma unroll
            for (int kq = 0; kq < 16; ++kq) {
                const unsigned short* cur = wlds[kq & 1];
                if (kq + 1 < 16)
                    stage_chunk(w1c + (kq + 1) * 8192, wlds[(kq + 1) & 1], w, lane);
                short8 b[4], a[2];
#pragma unroll
                for (int nt = 0; nt < 4; ++nt)
                    b[nt] = *reinterpret_cast<const short8*>(
                        cur + (nw * 64 + nt * 16 + l16) * 32 + quad * 8);
#pragma unroll
                for (int mt = 0; mt < 2; ++mt)
                    a[mt] = *reinterpret_cast<const short8*>(
                        &xs[mw * 32 + mt * 16 + l16][kq * 32 + quad * 8]);
#pragma unroll
                for (int mt = 0; mt < 2; ++mt)
#pragma unroll
                    for (int nt = 0; nt < 4; ++nt)
                        acc[mt][nt] = __builtin_amdgcn_mfma_f32_16x16x32_bf16(
                            a[mt], b[nt], acc[mt][nt], 0, 0, 0);
                __syncthreads();
            }

            // silu + gate -> hs
#pragma unroll
            for (int mt = 0; mt < 2; ++mt)
#pragma unroll
                for (int nt = 0; nt < 4; ++nt) {
                    int hcol = nw * 64 + nt * 16 + l16;
                    float bb = b1[j * 256 + hcol];
#pragma unroll
                    for (int r = 0; r < 4; ++r) {
                        int row = mw * 32 + mt * 16 + quad * 4 + r;
                        float v = acc[mt][nt][r] + bb;
                        float h = v / (1.f + __expf(-v));
                        hs[row][hcol] = f2bf(h * gr[mt * 4 + r]);
                    }
                }

            // ---- phase B: OUT += H'chunk @ W2^T (K=256)
            const unsigned short* w2c = W2pk + ((size_t)ex * 2 + j) * (8 * 8192);
            stage_chunk(w2c, wlds[0], w, lane);
            __syncthreads();                       // hs visible + DMA done

#pragma unroll
            for (int kq = 0; kq < 8; ++kq) {
                const unsigned short* cur = wlds[kq & 1];
                if (kq + 1 < 8)
                    stage_chunk(w2c + (kq + 1) * 8192, wlds[(kq + 1) & 1], w, lane);
                short8 b[4], a[2];
#pragma unroll
                for (int nt = 0; nt < 4; ++nt)
                    b[nt] = *reinterpret_cast<const short8*>(
                        cur + (nw * 64 + nt * 16 + l16) * 32 + quad * 8);
#pragma unroll
                for (int mt = 0; mt < 2; ++mt)
                    a[mt] = *reinterpret_cast<const short8*>(
                        &hs[mw * 32 + mt * 16 + l16][kq * 32 + quad * 8]);
#pragma unroll
                for (int mt = 0; mt < 2; ++mt)
#pragma unroll
                    for (int nt = 0; nt < 4; ++nt)
                        outacc[mt][nt] = __builtin_amdgcn_mfma_f32_16x16x32_bf16(
                            a[mt], b[nt], outacc[mt][nt], 0, 0, 0);
                __syncthreads();
            }
        }

        // ---- + gate * b2
#pragma unroll
        for (int mt = 0; mt < 2; ++mt)
#pragma unroll
            for (int nt = 0; nt < 4; ++nt) {
                float bb = b2[nw * 64 + nt * 16 + l16];
#pragma unroll
                for (int r = 0; r < 4; ++r)
                    outacc[mt][nt][r] += gr[mt * 4 + r] * bb;
            }
    }

    // write Y nontemporal (write-once stream)
#pragma unroll
    for (int mt = 0; mt < 2; ++mt)
#pragma unroll
        for (int nt = 0; nt < 4; ++nt)
#pragma unroll
            for (int r = 0; r < 4; ++r) {
                int row = mw * 32 + mt * 16 + quad * 4 + r;
                int gi = idxs[row];
                if (gi >= 0)
                    __builtin_nontemporal_store(outacc[mt][nt][r],
                        Y + (size_t)gi * OUT_F + nw * 64 + nt * 16 + l16);
            }
}

extern "C" void kernel_launch(void* const* d_in, const int* in_sizes, int n_in,
                              void* d_out, int out_size, void* d_ws, size_t ws_size,
                              hipStream_t stream) {
    const float* X       = (const float*)d_in[0];
    const int*   species = (const int*)d_in[1];
    const float* emb     = (const float*)d_in[2];
    const float* Wr      = (const float*)d_in[3];
    const float* rW1     = (const float*)d_in[4];
    const float* rb1     = (const float*)d_in[5];
    const float* rW2     = (const float*)d_in[6];
    const float* rb2     = (const float*)d_in[7];
    const float* sW1     = (const float*)d_in[8];
    const float* sb1     = (const float*)d_in[9];
    const float* sW2     = (const float*)d_in[10];
    const float* sb2     = (const float*)d_in[11];
    float* Y = (float*)d_out;
    const int N = in_sizes[1];

    const int TMAX = (N + 15 * 64 + 63) / 64;     // 64-padded buckets
    const int CAP  = TMAX * 64;

    size_t o = 0;
    auto take = [&](size_t bytes) { size_t r = o; o += (bytes + 255) & ~(size_t)255; return r; };
    char* ws = (char*)d_ws;
    unsigned short* w1bf   = (unsigned short*)(ws + take((size_t)8 * HID * IN_F * 2));
    unsigned short* w2bf   = (unsigned short*)(ws + take((size_t)8 * OUT_F * HID * 2));
    int*   pid      = (int*)  (ws + take((size_t)N * 4));
    float* gA       = (float*)(ws + take((size_t)N * 4));
    float* gB       = (float*)(ws + take((size_t)N * 4));
    int*   counts   = (int*)  (ws + take(64));
    int*   cursors  = (int*)  (ws + take(64));
    int*   offs     = (int*)  (ws + take(64));
    int*   idxl     = (int*)  (ws + take((size_t)CAP * 4));
    float* gAl      = (float*)(ws + take((size_t)CAP * 4));
    float* gBl      = (float*)(ws + take((size_t)CAP * 4));
    int*   tile_pair= (int*)  (ws + take((size_t)TMAX * 4));

    k_cvt_w1<<<(8 * HID * IN_F) / 256, 256, 0, stream>>>(rW1, sW1, w1bf);
    k_cvt_w2<<<(8 * OUT_F * HID) / 256, 256, 0, stream>>>(rW2, sW2, w2bf);
    k_fill<<<(CAP + 255) / 256, 256, 0, stream>>>(counts, cursors, idxl, tile_pair, CAP, TMAX);
    k_router<<<(N + 255) / 256, 256, 0, stream>>>(species, emb, Wr, pid, gA, gB, counts, N);
    k_scan<<<1, 256, 0, stream>>>(counts, offs, tile_pair, TMAX);
    k_scatter<<<(N + 255) / 256, 256, 0, stream>>>(pid, gA, gB, offs, cursors, idxl, gAl, gBl, N);
    k_moe<<<TMAX, 512, 0, stream>>>(X, w1bf, w2bf, idxl, gAl, gBl, tile_pair,
                                    rb1, rb2, sb1, sb2, Y);
}

// Round 4
// 839.944 us; speedup vs baseline: 1.7522x; 1.1934x over previous
//
#include <hip/hip_runtime.h>
#include <hip/hip_bf16.h>

// MoEReadout round 8 (= round 7 + vmcnt hardening): pair-bucketed 64-atom
// tiles, 8-wave blocks.
//  - Weights stream through a 3-deep LDS chunk pipeline via global_load_lds,
//    counted s_waitcnt vmcnt(2) + raw s_barrier per chunk (never drain to 0).
//  - Bank swizzle baked into the packed W layout (16B slot ^= (row>>1)&3):
//    the linear DMA copy preserves it, ds_read applies the same XOR ->
//    per-8-lane service group hits all 8 16B slots of the 128B stripe
//    (balanced) instead of 2 (4-way conflict).
//  - W1(16 chunks)+W2(8 chunks) per (expert,j) form one 24-chunk stream.
//  - Explicit vmcnt(0) after X staging so prologue DMA accounting is exact.
//  - XCD-chunked bijective blockIdx swizzle kept (weights L2-resident).

typedef __attribute__((ext_vector_type(8))) short short8;   // 8 x bf16
typedef __attribute__((ext_vector_type(4))) float f32x4;    // MFMA acc / 16B load

#define IN_F 512
#define HID  512
#define OUT_F 256
#define TILE 64
#define CH   8192   // shorts per 16KB chunk (256 rows x 32 cols)

#define WAIT_LGKM0 asm volatile("s_waitcnt lgkmcnt(0)" ::: "memory")
#define WAIT_VM2   asm volatile("s_waitcnt vmcnt(2)"   ::: "memory")
#define WAIT_VM0   asm volatile("s_waitcnt vmcnt(0)"   ::: "memory")

__device__ inline unsigned short f2bf(float f) {
    __hip_bfloat16 h = __float2bfloat16(f);
    return *reinterpret_cast<unsigned short*>(&h);
}

// CK-style address-space casts for global_load_lds (direct-to-LDS DMA).
__device__ __forceinline__ void dma16(const unsigned short* g, unsigned short* l) {
    __builtin_amdgcn_global_load_lds(
        (const __attribute__((address_space(1))) unsigned int*)(unsigned long long)(const void*)g,
        (__attribute__((address_space(3))) unsigned int*)(unsigned int)(unsigned long long)(void*)l,
        16, 0, 0);
}

// Stage one 16KB chunk into LDS. Wave w copies 2KB (2 x global_load_lds,
// each: uniform LDS base, HW appends lane*16B; global side lane*16B too).
__device__ __forceinline__ void stage_chunk(const unsigned short* g,
                                            unsigned short* l, int w, int lane) {
    dma16(g + w * 1024 +       lane * 8, l + w * 1024);
    dma16(g + w * 1024 + 512 + lane * 8, l + w * 1024 + 512);
}

// ---------- weight conversion + fragment packing (with bank swizzle) ----------
// W1 packed: [ex(8)][j(2)][kq(16)][row(256)][32 cols], where within a row the
// 16B slot s (col>>3) is stored at s ^ ((row>>1)&3). Inverted here (XOR is an
// involution): iterate dst index, recover src (row,col).
__global__ void k_cvt_w1(const float* __restrict__ rW1, const float* __restrict__ sW1,
                         unsigned short* __restrict__ dst) {
    int i = blockIdx.x * 256 + threadIdx.x;
    int low3 = i & 7;
    int sw   = (i >> 3) & 3;
    int row  = (i >> 5) & 255;
    int kq   = (i >> 13) & 15;
    int j    = (i >> 17) & 1;
    int ex   = i >> 18;
    int col  = ((sw ^ ((row >> 1) & 3)) << 3) + low3;
    int hrow = j * 256 + row;
    int kcol = kq * 32 + col;
    float v = (ex < 6) ? rW1[((size_t)ex * 512 + hrow) * 512 + kcol]
                       : sW1[((size_t)(ex - 6) * 512 + hrow) * 512 + kcol];
    dst[i] = f2bf(v);
}

// W2 packed: [ex(8)][j(2)][kq(8)][row(256)][32 cols], same in-row swizzle.
__global__ void k_cvt_w2(const float* __restrict__ rW2, const float* __restrict__ sW2,
                         unsigned short* __restrict__ dst) {
    int i = blockIdx.x * 256 + threadIdx.x;
    int low3 = i & 7;
    int sw   = (i >> 3) & 3;
    int row  = (i >> 5) & 255;
    int kq   = (i >> 13) & 7;
    int j    = (i >> 16) & 1;
    int ex   = i >> 17;
    int col  = ((sw ^ ((row >> 1) & 3)) << 3) + low3;
    int kcol = j * 256 + kq * 32 + col;
    float v = (ex < 6) ? rW2[((size_t)ex * 256 + row) * 512 + kcol]
                       : sW2[((size_t)(ex - 6) * 256 + row) * 512 + kcol];
    dst[i] = f2bf(v);
}

// ---------- bucket state init ----------
__global__ void k_fill(int* __restrict__ counts, int* __restrict__ cursors,
                       int* __restrict__ idxl, int* __restrict__ tile_pair,
                       int CAP, int TMAX) {
    int i = blockIdx.x * 256 + threadIdx.x;
    if (i < 16) { counts[i] = 0; cursors[i] = 0; }
    if (i < TMAX) tile_pair[i] = -1;
    if (i < CAP) idxl[i] = -1;
}

// ---------- router: top-2 -> pair id + gates ----------
__global__ void k_router(const int* __restrict__ species, const float* __restrict__ emb,
                         const float* __restrict__ Wr,
                         int* __restrict__ pid, float* __restrict__ gA, float* __restrict__ gB,
                         int* __restrict__ counts, int N) {
    __shared__ int lcnt[16];
    int tid = threadIdx.x;
    if (tid < 16) lcnt[tid] = 0;
    __syncthreads();
    int i = blockIdx.x * 256 + tid;
    if (i < N) {
        int z = species[i];
        float u[16];
#pragma unroll
        for (int k = 0; k < 16; ++k) {
            float v = emb[z * 16 + k];
            u[k] = v / (1.f + __expf(-v));               // silu
        }
        float s[6];
        float mx = -1e30f;
#pragma unroll
        for (int e = 0; e < 6; ++e) {
            float a = 0.f;
#pragma unroll
            for (int k = 0; k < 16; ++k) a += u[k] * Wr[e * 16 + k];
            s[e] = a;
            mx = fmaxf(mx, a);
        }
        float sum = 0.f;
#pragma unroll
        for (int e = 0; e < 6; ++e) { s[e] = __expf(s[e] - mx); sum += s[e]; }
        float inv = 1.f / sum;
        int i0 = 0;
#pragma unroll
        for (int e = 1; e < 6; ++e) if (s[e] > s[i0]) i0 = e;
        int i1 = (i0 == 0) ? 1 : 0;
#pragma unroll
        for (int e = 0; e < 6; ++e) if (e != i0 && s[e] > s[i1]) i1 = e;
        float g0 = s[i0] * inv, g1 = s[i1] * inv;
        int a = min(i0, i1), b = max(i0, i1);
        const int PB[5] = {0, 5, 9, 12, 14};
        int p = PB[a] + (b - a - 1);
        pid[i] = p;
        gA[i] = (a == i0) ? g0 : g1;
        gB[i] = (a == i0) ? g1 : g0;
        atomicAdd(&lcnt[p], 1);
    }
    __syncthreads();
    if (tid < 15 && lcnt[tid] > 0) atomicAdd(&counts[tid], lcnt[tid]);
}

// ---------- scan: 64-padded bucket offsets + tile->pair map ----------
__global__ void k_scan(const int* __restrict__ counts, int* __restrict__ offs,
                       int* __restrict__ tile_pair, int TMAX) {
    __shared__ int so[16];
    if (threadIdx.x == 0) {
        int acc = 0;
        for (int p = 0; p < 15; ++p) { so[p] = acc; acc += (counts[p] + 63) & ~63; }
        so[15] = acc;
        for (int p = 0; p < 16; ++p) offs[p] = so[p];
    }
    __syncthreads();
    for (int t = threadIdx.x; t < TMAX; t += blockDim.x) {
        int t64 = t * 64;
        if (t64 < so[15]) {
            int p = 0;
            while (!(t64 >= so[p] && t64 < so[p + 1])) ++p;
            tile_pair[t] = p;
        }
    }
}

// ---------- scatter atoms into pair buckets ----------
__global__ void k_scatter(const int* __restrict__ pid, const float* __restrict__ gA,
                          const float* __restrict__ gB, const int* __restrict__ offs,
                          int* __restrict__ cursors, int* __restrict__ idxl,
                          float* __restrict__ gAl, float* __restrict__ gBl, int N) {
    __shared__ int lcnt[16], lbase[16];
    int tid = threadIdx.x;
    if (tid < 16) lcnt[tid] = 0;
    __syncthreads();
    int i = blockIdx.x * 256 + tid;
    int p = -1, rank = 0;
    if (i < N) { p = pid[i]; rank = atomicAdd(&lcnt[p], 1); }
    __syncthreads();
    if (tid < 15 && lcnt[tid] > 0) lbase[tid] = atomicAdd(&cursors[tid], lcnt[tid]);
    __syncthreads();
    if (i < N) {
        int slot = offs[p] + lbase[p] + rank;
        idxl[slot] = i; gAl[slot] = gA[i]; gBl[slot] = gB[i];
    }
}

// ---------- fused MoE MLP over pair-homogeneous 64-atom tiles ----------
// 512 threads = 8 waves (mw = w>>2 atom half, nw = w&3 64-col group).
// LDS ~150KB -> 1 block/CU (2 waves/SIMD). Weights stream through a
// 3x16KB rotating buffer; per-chunk: {lgkm0; vmcnt(2); s_barrier;
// stage(c+2); ds_read c; 8 MFMA}. vmcnt retires in issue order, so
// vmcnt(2) == "chunk c landed" while c+1,c+2 stay in flight.
__global__ __launch_bounds__(512, 2) void k_moe(
    const float* __restrict__ X,
    const unsigned short* __restrict__ W1pk,     // packed+swizzled, see k_cvt_w1
    const unsigned short* __restrict__ W2pk,     // packed+swizzled, see k_cvt_w2
    const int* __restrict__ idxl, const float* __restrict__ gAl,
    const float* __restrict__ gBl, const int* __restrict__ tile_pair,
    const float* __restrict__ rb1, const float* __restrict__ rb2,
    const float* __restrict__ sb1, const float* __restrict__ sb2,
    float* __restrict__ Y)
{
    // Bijective XCD-chunked swizzle (m204): per-XCD working set ~1 pair.
    int t;
    {
        const int nwg = (int)gridDim.x;
        const int q = nwg >> 3, r = nwg & 7;
        const int xcd = (int)blockIdx.x & 7;
        const int idx = (int)blockIdx.x >> 3;
        t = (xcd < r ? xcd * (q + 1) : r * (q + 1) + (xcd - r) * q) + idx;
    }
    const int p = tile_pair[t];
    if (p < 0) return;
    int ea = 0, eb = 1;
    {
        int pp = p;
#pragma unroll
        for (int a = 0; a < 5; ++a) {
            int span = 5 - a;
            if (pp < span) { ea = a; eb = a + 1 + pp; break; }
            pp -= span;
        }
    }

    __shared__ __align__(16) unsigned short xs[TILE][520];     // 66.6 KB
    __shared__ __align__(16) unsigned short hs[TILE][264];     // 33.8 KB
    __shared__ __align__(16) unsigned short wlds[3][CH];       // 48 KB
    __shared__ float gsA[TILE], gsB[TILE];
    __shared__ int idxs[TILE];

    const int tid = threadIdx.x;
    if (tid < TILE) {
        int slot = t * TILE + tid;
        int gi = idxl[slot];
        idxs[tid] = gi;
        gsA[tid] = (gi >= 0) ? gAl[slot] : 0.f;
        gsB[tid] = (gi >= 0) ? gBl[slot] : 0.f;
    }
    __syncthreads();

    // stage X tile (fp32 -> bf16), nontemporal. Published by the first
    // in-loop {lgkm0; barrier} below.
    for (int i = tid; i < TILE * 128; i += 512) {
        int r = i >> 7, c4 = i & 127;
        int gi = idxs[r]; if (gi < 0) gi = 0;
        f32x4 v = __builtin_nontemporal_load(
            reinterpret_cast<const f32x4*>(X + (size_t)gi * IN_F) + c4);
        ushort4 pk;
        pk.x = f2bf(v.x); pk.y = f2bf(v.y); pk.z = f2bf(v.z); pk.w = f2bf(v.w);
        *reinterpret_cast<ushort4*>(&xs[r][c4 * 4]) = pk;
    }
    // Hardening: make vmcnt accounting exact for the chunk pipeline (all X
    // loads structurally consumed above, so this is ~free).
    WAIT_VM0;

    const int w    = tid >> 6;        // wave 0..7
    const int lane = tid & 63;
    const int mw   = w >> 2;          // atom half (0..1)
    const int nw   = w & 3;           // 64-col group (0..3)
    const int quad = lane >> 4;
    const int l16  = lane & 15;
    // swizzled 16B-slot offset for W reads: slot quad ^ ((row>>1)&3);
    // row = nw*64+nt*16+l16 -> (row>>1)&3 == (l16>>1)&3 (nt*16,nw*64 even*8)
    const int swz  = ((quad ^ ((l16 >> 1) & 3)) << 3);
    const int wrow = (nw * 64 + l16) * 32;   // + nt*512 per fragment

    f32x4 outacc[2][4] = {};          // 32 atoms x 64 out cols per wave

    for (int ei = 0; ei < 4; ++ei) {
        const int ex = (ei == 0) ? ea : (ei == 1) ? eb : (ei + 4);  // 6,7 shared
        const float* b1 = (ex < 6) ? rb1 + ex * HID   : sb1 + (ex - 6) * HID;
        const float* b2 = (ex < 6) ? rb2 + ex * OUT_F : sb2 + (ex - 6) * OUT_F;

        float gr[8];
#pragma unroll
        for (int mt = 0; mt < 2; ++mt)
#pragma unroll
            for (int r = 0; r < 4; ++r) {
                int row = mw * 32 + mt * 16 + quad * 4 + r;
                gr[mt * 4 + r] = (ei == 0) ? gsA[row] : (ei == 1) ? gsB[row] : 1.f;
            }

        for (int j = 0; j < 2; ++j) {              // H column chunks of 256
            const unsigned short* w1c = W1pk + ((size_t)ex * 2 + j) * (16 * CH);
            const unsigned short* w2c = W2pk + ((size_t)ex * 2 + j) * (8 * CH);

            // prologue: chunks 0,1 in flight (4 vm ops)
            stage_chunk(w1c,      wlds[0], w, lane);
            stage_chunk(w1c + CH, wlds[1], w, lane);

            f32x4 acc[2][4] = {};

            // ---- phase A: chunks 0..15 (W1), acc += X @ W1^T
#pragma unroll
            for (int c = 0; c < 16; ++c) {
                WAIT_LGKM0;                       // my prior LDS ops retired
                WAIT_VM2;                         // chunk c landed (in-order)
                __builtin_amdgcn_s_barrier();     // all waves: c visible,
                                                  // buf (c+2)%3 free to write
                if (c + 2 < 16)
                    stage_chunk(w1c + (c + 2) * CH, wlds[(c + 2) % 3], w, lane);
                else
                    stage_chunk(w2c + (c + 2 - 16) * CH, wlds[(c + 2) % 3], w, lane);
                const unsigned short* cur = wlds[c % 3];
                short8 b[4], a[2];
#pragma unroll
                for (int nt = 0; nt < 4; ++nt)
                    b[nt] = *reinterpret_cast<const short8*>(cur + wrow + nt * 512 + swz);
#pragma unroll
                for (int mt = 0; mt < 2; ++mt)
                    a[mt] = *reinterpret_cast<const short8*>(
                        &xs[mw * 32 + mt * 16 + l16][c * 32 + quad * 8]);
#pragma unroll
                for (int mt = 0; mt < 2; ++mt)
#pragma unroll
                    for (int nt = 0; nt < 4; ++nt)
                        acc[mt][nt] = __builtin_amdgcn_mfma_f32_16x16x32_bf16(
                            a[mt], b[nt], acc[mt][nt], 0, 0, 0);
            }

            // silu + gate -> hs (own disjoint region; published at c=16 barrier)
#pragma unroll
            for (int mt = 0; mt < 2; ++mt)
#pragma unroll
                for (int nt = 0; nt < 4; ++nt) {
                    int hcol = nw * 64 + nt * 16 + l16;
                    float bb = b1[j * 256 + hcol];
#pragma unroll
                    for (int r = 0; r < 4; ++r) {
                        int row = mw * 32 + mt * 16 + quad * 4 + r;
                        float v = acc[mt][nt][r] + bb;
                        float h = v / (1.f + __expf(-v));
                        hs[row][hcol] = f2bf(h * gr[mt * 4 + r]);
                    }
                }

            // ---- phase B: chunks 16..23 (W2), outacc += H' @ W2^T
#pragma unroll
            for (int c = 16; c < 24; ++c) {
                WAIT_LGKM0;                       // incl. my hs ds_writes
                if (c < 23) { WAIT_VM2; } else { WAIT_VM0; }
                __builtin_amdgcn_s_barrier();
                if (c + 2 < 24)
                    stage_chunk(w2c + (c + 2 - 16) * CH, wlds[(c + 2) % 3], w, lane);
                const unsigned short* cur = wlds[c % 3];
                short8 b[4], a[2];
#pragma unroll
                for (int nt = 0; nt < 4; ++nt)
                    b[nt] = *reinterpret_cast<const short8*>(cur + wrow + nt * 512 + swz);
#pragma unroll
                for (int mt = 0; mt < 2; ++mt)
                    a[mt] = *reinterpret_cast<const short8*>(
                        &hs[mw * 32 + mt * 16 + l16][(c - 16) * 32 + quad * 8]);
#pragma unroll
                for (int mt = 0; mt < 2; ++mt)
#pragma unroll
                    for (int nt = 0; nt < 4; ++nt)
                        outacc[mt][nt] = __builtin_amdgcn_mfma_f32_16x16x32_bf16(
                            a[mt], b[nt], outacc[mt][nt], 0, 0, 0);
            }
        }

        // ---- + gate * b2
#pragma unroll
        for (int mt = 0; mt < 2; ++mt)
#pragma unroll
            for (int nt = 0; nt < 4; ++nt) {
                float bb = b2[nw * 64 + nt * 16 + l16];
#pragma unroll
                for (int r = 0; r < 4; ++r)
                    outacc[mt][nt][r] += gr[mt * 4 + r] * bb;
            }
    }

    // write Y nontemporal (write-once stream)
#pragma unroll
    for (int mt = 0; mt < 2; ++mt)
#pragma unroll
        for (int nt = 0; nt < 4; ++nt)
#pragma unroll
            for (int r = 0; r < 4; ++r) {
                int row = mw * 32 + mt * 16 + quad * 4 + r;
                int gi = idxs[row];
                if (gi >= 0)
                    __builtin_nontemporal_store(outacc[mt][nt][r],
                        Y + (size_t)gi * OUT_F + nw * 64 + nt * 16 + l16);
            }
}

extern "C" void kernel_launch(void* const* d_in, const int* in_sizes, int n_in,
                              void* d_out, int out_size, void* d_ws, size_t ws_size,
                              hipStream_t stream) {
    const float* X       = (const float*)d_in[0];
    const int*   species = (const int*)d_in[1];
    const float* emb     = (const float*)d_in[2];
    const float* Wr      = (const float*)d_in[3];
    const float* rW1     = (const float*)d_in[4];
    const float* rb1     = (const float*)d_in[5];
    const float* rW2     = (const float*)d_in[6];
    const float* rb2     = (const float*)d_in[7];
    const float* sW1     = (const float*)d_in[8];
    const float* sb1     = (const float*)d_in[9];
    const float* sW2     = (const float*)d_in[10];
    const float* sb2     = (const float*)d_in[11];
    float* Y = (float*)d_out;
    const int N = in_sizes[1];

    const int TMAX = (N + 15 * 64 + 63) / 64;     // 64-padded buckets
    const int CAP  = TMAX * 64;

    size_t o = 0;
    auto take = [&](size_t bytes) { size_t r = o; o += (bytes + 255) & ~(size_t)255; return r; };
    char* ws = (char*)d_ws;
    unsigned short* w1bf   = (unsigned short*)(ws + take((size_t)8 * HID * IN_F * 2));
    unsigned short* w2bf   = (unsigned short*)(ws + take((size_t)8 * OUT_F * HID * 2));
    int*   pid      = (int*)  (ws + take((size_t)N * 4));
    float* gA       = (float*)(ws + take((size_t)N * 4));
    float* gB       = (float*)(ws + take((size_t)N * 4));
    int*   counts   = (int*)  (ws + take(64));
    int*   cursors  = (int*)  (ws + take(64));
    int*   offs     = (int*)  (ws + take(64));
    int*   idxl     = (int*)  (ws + take((size_t)CAP * 4));
    float* gAl      = (float*)(ws + take((size_t)CAP * 4));
    float* gBl      = (float*)(ws + take((size_t)CAP * 4));
    int*   tile_pair= (int*)  (ws + take((size_t)TMAX * 4));

    k_cvt_w1<<<(8 * HID * IN_F) / 256, 256, 0, stream>>>(rW1, sW1, w1bf);
    k_cvt_w2<<<(8 * OUT_F * HID) / 256, 256, 0, stream>>>(rW2, sW2, w2bf);
    k_fill<<<(CAP + 255) / 256, 256, 0, stream>>>(counts, cursors, idxl, tile_pair, CAP, TMAX);
    k_router<<<(N + 255) / 256, 256, 0, stream>>>(species, emb, Wr, pid, gA, gB, counts, N);
    k_scan<<<1, 256, 0, stream>>>(counts, offs, tile_pair, TMAX);
    k_scatter<<<(N + 255) / 256, 256, 0, stream>>>(pid, gA, gB, offs, cursors, idxl, gAl, gBl, N);
    k_moe<<<TMAX, 512, 0, stream>>>(X, w1bf, w2bf, idxl, gAl, gBl, tile_pair,
                                    rb1, rb2, sb1, sb2, Y);
}